// Round 7
// baseline (286.282 us; speedup 1.0000x reference)
//
#include <hip/hip_runtime.h>
#include <math.h>

// out[b] = log( sum_kk (w[kk>>8]*W0[kk,x0[b]]) * W1[kk,x1[b]] ),  kk in [0,65536)
//
// gemm: 1024 blocks x 256 threads (4 waves), FOUR blocks/CU. Block =
// (split = one latent k, 256 kk) x quadrant (c0 half, c1 half): tile 128x128,
// wave tile 64x64 (acc = 64 VGPR). Small, uniform, branch-free register
// footprint (~130 VGPR) -> no spills (R6's 86 MB scratch traffic). Quadrants
// of a split share an XCD (blk%8 == split%8) and are co-resident -> the 2x
// logical W read is L2-served. Double-buffered LDS, register prefetch, one
// barrier/iter. Epilogue: 4-phase LDS dump + pair gather -> P[1024][1024],
// w_sum folded here. finish reduces + log.

#define NITER 8
#define BK    32

typedef float  f32x4  __attribute__((ext_vector_type(4)));
typedef short  bf16x8 __attribute__((ext_vector_type(8)));

static __device__ __forceinline__ short f2bf(float f) {
    // RNE fp32 -> bf16 (positive probabilities; no NaN/Inf)
    unsigned u = __builtin_bit_cast(unsigned, f);
    u += 0x7fffu + ((u >> 16) & 1u);
    return (short)(u >> 16);
}

__global__ __launch_bounds__(256, 4) void hclt_gemm(
    const int* __restrict__ x, const float* __restrict__ W,
    const float* __restrict__ wsum, float* __restrict__ P)
{
    // dbuf staging: buf c at smem + c*16384 (As 8K | Bs 8K).
    // epilogue reuses smem as G[64][68] floats (17408 B).
    __shared__ __align__(16) char smem[32768];
    __shared__ int pairs[1024];
    float* const G = (float*)smem;

    const int blk   = blockIdx.x;        // 0..1023
    const int split = blk & 255;
    const int quad  = blk >> 8;          // 0..3
    const int c0h   = quad & 1, c1h = quad >> 1;

    const float* __restrict__ Ag = W + (long)split * 65536 + c0h * 128;
    const float* __restrict__ Bg = W + 16777216 + (long)split * 65536 + c1h * 128;

    const int t    = threadIdx.x;
    const int lane = t & 63;
    const int wv   = t >> 6;             // wave 0..3

    // observed pairs -> LDS (epilogue only; visible after first barrier)
#pragma unroll
    for (int jj = 0; jj < 4; ++jj) {
        const int2 p = ((const int2*)x)[t + 256 * jj];
        pairs[t + 256 * jj] = (p.x << 8) | p.y;
    }

    // staging geometry (uniform for ALL threads -- no role branches):
    // thread stages c = l5*4..+3 at k rows o*4..+3, for both A and B.
    const int l5 = t & 31;               // c-quad
    const int o  = t >> 5;               // 0..7 -> k rows o*4 + r
    const int sg = ((o >> 1) ^ l5) & 3;  // swizzled 16B group (k-octet o>>1)
    const int so = (o & 1) * 8;          // 8B half within group

    // compute geometry: wave tile 64x64
    const int wc0 = (wv & 1) * 64;
    const int wc1 = (wv >> 1) * 64;
    const int ml  = lane & 15;
    const int qd  = lane >> 4;

    f32x4 acc[4][4];
#pragma unroll
    for (int i = 0; i < 4; ++i)
#pragma unroll
        for (int j = 0; j < 4; ++j) acc[i][j] = (f32x4){0.f, 0.f, 0.f, 0.f};

    float4 pa[4], pb[4];                 // 32 VGPRs of prefetch

    // ---- prologue: load + stage iter 0 into buf 0 ----
#pragma unroll
    for (int r = 0; r < 4; ++r) {
        pa[r] = *(const float4*)(Ag + (long)(o * 4 + r) * 256 + l5 * 4);
        pb[r] = *(const float4*)(Bg + (long)(o * 4 + r) * 256 + l5 * 4);
    }
    {
        char* const Ab = smem;
        char* const Bb = smem + 8192;
#pragma unroll
        for (int j = 0; j < 4; ++j) {
            const int c = l5 * 4 + j;
            short4 av, bv;
            av.x = f2bf(pa[0][j]); av.y = f2bf(pa[1][j]);
            av.z = f2bf(pa[2][j]); av.w = f2bf(pa[3][j]);
            bv.x = f2bf(pb[0][j]); bv.y = f2bf(pb[1][j]);
            bv.z = f2bf(pb[2][j]); bv.w = f2bf(pb[3][j]);
            *(short4*)(Ab + c * 64 + sg * 16 + so) = av;
            *(short4*)(Bb + c * 64 + sg * 16 + so) = bv;
        }
    }
    __syncthreads();

    // ---- main loop: one MFMA k-step (32) per iter, dbuf, 1 barrier/iter ----
#pragma unroll 1
    for (int it = 0; it < NITER; ++it) {
        const int cur = it & 1;
        if (it + 1 < NITER) {            // prefetch next iter into regs
            const long k0 = (long)(it + 1) * BK;
#pragma unroll
            for (int r = 0; r < 4; ++r) {
                pa[r] = *(const float4*)(Ag + (k0 + o * 4 + r) * 256 + l5 * 4);
                pb[r] = *(const float4*)(Bg + (k0 + o * 4 + r) * 256 + l5 * 4);
            }
        }
        // compute current from LDS
        {
            char* const Ab = smem + cur * 16384;
            char* const Bb = Ab + 8192;
            bf16x8 afr[4];
#pragma unroll
            for (int mi = 0; mi < 4; ++mi) {
                const int c = wc0 + mi * 16 + ml;
                afr[mi] = *(const bf16x8*)(Ab + c * 64 + ((qd ^ (c >> 2)) & 3) * 16);
            }
#pragma unroll
            for (int ni = 0; ni < 4; ++ni) {
                const int c = wc1 + ni * 16 + ml;
                const bf16x8 bfr =
                    *(const bf16x8*)(Bb + c * 64 + ((qd ^ (c >> 2)) & 3) * 16);
#pragma unroll
                for (int mi = 0; mi < 4; ++mi)
                    acc[mi][ni] = __builtin_amdgcn_mfma_f32_16x16x32_bf16(
                        afr[mi], bfr, acc[mi][ni], 0, 0, 0);
            }
        }
        // stage next iter into the other buffer (nobody is reading it)
        if (it + 1 < NITER) {
            char* const Ab = smem + (1 - cur) * 16384;
            char* const Bb = Ab + 8192;
#pragma unroll
            for (int j = 0; j < 4; ++j) {
                const int c = l5 * 4 + j;
                short4 av, bv;
                av.x = f2bf(pa[0][j]); av.y = f2bf(pa[1][j]);
                av.z = f2bf(pa[2][j]); av.w = f2bf(pa[3][j]);
                bv.x = f2bf(pb[0][j]); bv.y = f2bf(pb[1][j]);
                bv.z = f2bf(pb[2][j]); bv.w = f2bf(pb[3][j]);
                *(short4*)(Ab + c * 64 + sg * 16 + so) = av;
                *(short4*)(Bb + c * 64 + sg * 16 + so) = bv;
            }
            __syncthreads();
        }
    }

    // ---- epilogue: 4 phases, wave ph dumps its 64x64 tile, all gather ----
    // C/D layout: local c0 = mi*16 + qd*4 + r, local c1 = ni*16 + ml
    const float wk = wsum[split];
    float pv0 = 0.f, pv1 = 0.f, pv2 = 0.f, pv3 = 0.f;
#pragma unroll 1
    for (int ph = 0; ph < 4; ++ph) {
        __syncthreads();
        if (wv == ph) {
#pragma unroll
            for (int mi = 0; mi < 4; ++mi)
#pragma unroll
                for (int ni = 0; ni < 4; ++ni)
#pragma unroll
                    for (int r = 0; r < 4; ++r)
                        G[(mi * 16 + qd * 4 + r) * 68 + (ni * 16 + ml)] = acc[mi][ni][r];
        }
        __syncthreads();
#pragma unroll
        for (int jj = 0; jj < 4; ++jj) {
            const int pr = pairs[t + 256 * jj];
            const int c0 = pr >> 8, c1 = pr & 255;
            if ((c0 >> 7) == c0h && (c1 >> 7) == c1h &&
                ((((c0 >> 6) & 1) | (((c1 >> 6) & 1) << 1)) == ph)) {
                const float v = G[(c0 & 63) * 68 + (c1 & 63)];
                if (jj == 0) pv0 = v; else if (jj == 1) pv1 = v;
                else if (jj == 2) pv2 = v; else pv3 = v;
            }
        }
    }
    float* __restrict__ Pb = P + (size_t)blk * 1024;
    Pb[t]       = pv0 * wk;              // coalesced, no atomics
    Pb[t + 256] = pv1 * wk;
    Pb[t + 512] = pv2 * wk;
    Pb[t + 768] = pv3 * wk;
}

// Reduce 1024 per-block partials per output + log.
// 16 blocks x 256 threads; block handles 64 outputs, 4 threads each.
__global__ __launch_bounds__(256) void hclt_finish(
    const float* __restrict__ P, float* __restrict__ out)
{
    __shared__ float red[4][64];
    const int l = threadIdx.x & 63;
    const int q = threadIdx.x >> 6;
    const int i = blockIdx.x * 64 + l;
    float s = 0.f;
#pragma unroll 8
    for (int m = 0; m < 256; ++m)
        s += P[(size_t)(q + 4 * m) * 1024 + i];
    red[q][l] = s;
    __syncthreads();
    if (q == 0)
        out[i] = logf((red[0][l] + red[1][l]) + (red[2][l] + red[3][l]));
}

extern "C" void kernel_launch(void* const* d_in, const int* in_sizes, int n_in,
                              void* d_out, int out_size, void* d_ws, size_t ws_size,
                              hipStream_t stream)
{
    const int*   x    = (const int*)d_in[0];     // [1024,2] int32
    const float* W    = (const float*)d_in[1];   // [2,256,256,256] fp32
    const float* wsum = (const float*)d_in[2];   // [256] fp32
    float* out = (float*)d_out;                  // [1024] fp32

    float* P = (float*)d_ws;                     // 1024 x 1024 floats = 4 MB

    hclt_gemm<<<dim3(1024), 256, 0, stream>>>(x, W, wsum, P);
    hclt_finish<<<dim3(16), 256, 0, stream>>>(P, out);
}